// Round 5
// baseline (607.270 us; speedup 1.0000x reference)
//
#include <hip/hip_runtime.h>

typedef unsigned short u16;
typedef __bf16 bf16x4 __attribute__((ext_vector_type(4)));
typedef __bf16 bf16x8 __attribute__((ext_vector_type(8)));
typedef float f32x4 __attribute__((ext_vector_type(4)));
typedef u16 u16x4 __attribute__((ext_vector_type(4)));
typedef u16 u16x8 __attribute__((ext_vector_type(8)));

#define AS1P(p) ((__attribute__((address_space(1))) void*)(unsigned long long)(p))
#define AS3P(p) ((__attribute__((address_space(3))) void*)(unsigned long long)(p))
#define MFMA16(a, b, c) __builtin_amdgcn_mfma_f32_16x16x32_bf16((a), (b), (c), 0, 0, 0)

__device__ __forceinline__ u16 f2b(float x) { return __builtin_bit_cast(u16, (__bf16)x); }
__device__ __forceinline__ float b2f(u16 u) {
  return __builtin_bit_cast(float, (unsigned)u << 16);
}

// ---------------- elementwise f32 -> bf16 ----------------
__global__ __launch_bounds__(256) void cvt_f32_bf16(const float* __restrict__ in,
                                                    u16* __restrict__ out, int n4) {
  int stride = gridDim.x * blockDim.x;
  for (int i = blockIdx.x * blockDim.x + threadIdx.x; i < n4; i += stride) {
    f32x4 v = *(const f32x4*)(in + (long)i * 4);
    u16x4 o;
    o[0] = f2b(v[0]); o[1] = f2b(v[1]); o[2] = f2b(v[2]); o[3] = f2b(v[3]);
    *(u16x4*)(out + (long)i * 4) = o;
  }
}

// ---------------- weight transpose f32[K][N] -> bf16[N][K] ----------------
__global__ __launch_bounds__(256) void wtrans(const float* __restrict__ W,
                                              u16* __restrict__ Wt, int K, int N) {
  __shared__ float tile[32][33];
  int nbk = K >> 5;
  int bk = blockIdx.x % nbk;
  int bn = blockIdx.x / nbk;
  int tx = threadIdx.x & 31, ty = threadIdx.x >> 5;  // 32 x 8
#pragma unroll
  for (int i = 0; i < 32; i += 8)
    tile[ty + i][tx] = W[(long)(bk * 32 + ty + i) * N + bn * 32 + tx];
  __syncthreads();
#pragma unroll
  for (int i = 0; i < 32; i += 8)
    Wt[(long)(bn * 32 + ty + i) * K + bk * 32 + tx] = f2b(tile[tx][ty + i]);
}

// ---------------- v transpose bf16 [8][256][1024] -> [8][1024][256], scaled by C/Se ---
__global__ __launch_bounds__(256) void vtrans(const u16* __restrict__ v, u16* __restrict__ vt) {
  __shared__ u16 tile[32][33];
  int bt = blockIdx.x & 7;          // Se/32
  int bd = (blockIdx.x >> 3) & 31;  // D/32
  int bc = blockIdx.x >> 8;         // 8
  int tx = threadIdx.x & 31, ty = threadIdx.x >> 5;
  const long vb = (long)bc * 256 * 1024;
  const long ob = (long)bc * 1024 * 256;
  const float RS = 1.0f / 64.0f;  // C/Se (exact pow2: no rounding)
#pragma unroll
  for (int i = 0; i < 32; i += 8)
    tile[ty + i][tx] = v[vb + (long)(bt * 32 + ty + i) * 1024 + bd * 32 + tx];
  __syncthreads();
#pragma unroll
  for (int i = 0; i < 32; i += 8)
    vt[ob + (long)(bd * 32 + ty + i) * 256 + bt * 32 + tx] =
        f2b(b2f(tile[tx][ty + i]) * RS);
}

// ---------------- K fragmentizer: kb[BC][Se][D] -> MFMA B-frag order -------------------
// frag id wv = ((((b*16+h)*8+ch)*4+c)*2+tsl)*2+ks ; element: lane*8 (16B/lane, coalesced)
__global__ __launch_bounds__(256) void kfrag_build(const u16* __restrict__ kb,
                                                   u16* __restrict__ kfrag) {
  int wv = ((int)blockIdx.x << 2) + (threadIdx.x >> 6);  // 0..4095
  int lane = threadIdx.x & 63, lr = lane & 15, lg = lane >> 4;
  int ks = wv & 1, tsl = (wv >> 1) & 1, c = (wv >> 2) & 3;
  int ch = (wv >> 4) & 7, h = (wv >> 7) & 15, b = (wv >> 11) & 1;
  const u16* src = kb + ((long)(c * 2 + b) * 256 + ch * 32 + tsl * 16 + lr) * 1024 +
                   h * 64 + ks * 32 + lg * 8;
  *(bf16x8*)(kfrag + (long)wv * 512 + lane * 8) = *(const bf16x8*)src;
}

// ---------------- V fragmentizer: vtb[BC][D][Se] -> MFMA B-frag order ------------------
// frag id wv = ((((b*16+h)*8+ch)*4+c)*4+dsu
__global__ __launch_bounds__(256) void vfrag_build(const u16* __restrict__ vtb,
                                                   u16* __restrict__ vfrag) {
  int wv = ((int)blockIdx.x << 2) + (threadIdx.x >> 6);  // 0..4095
  int lane = threadIdx.x & 63, lr = lane & 15, lg = lane >> 4;
  int dsu = wv & 3, c = (wv >> 2) & 3;
  int ch = (wv >> 4) & 7, h = (wv >> 7) & 15, b = (wv >> 11) & 1;
  const u16* src = vtb + ((long)(c * 2 + b) * 1024 + h * 64 + dsu * 16 + lr) * 256 +
                   ch * 32 + lg * 8;
  *(bf16x8*)(vfrag + (long)wv * 512 + lane * 8) = *(const bf16x8*)src;
}

// ---------------- GEMM: C[M,N] = A[M,K] @ Bt[N,K]^T (bf16 in, MFMA 16x16x32) ----------
// MODE 0: A bf16; write bf16 C*ascale.
// MODE 1: A bf16; write f32 C + bias[n] + resid[m*N+n].
// MODE 2: A f32 (converted to bf16 during reg-staging); write bf16 C*ascale.
template <int MODE>
__global__ __launch_bounds__(256) void gemm_bt(
    const u16* __restrict__ A, const float* __restrict__ Af,
    const u16* __restrict__ Bt,
    u16* __restrict__ outb, float* __restrict__ outf,
    const float* __restrict__ bias, const float* __restrict__ resid,
    int M, int N, int K, float ascale) {
  __shared__ u16 lA[128 * 64];  // [row][slot]; LDS slot s holds data k-slot s^(row&7)
  __shared__ u16 lB[128 * 64];
  const int tid = threadIdx.x;
  const int lane = tid & 63;
  const int wid = tid >> 6;
  const int wm = wid >> 1, wn = wid & 1;
  const int lr = lane & 15, lg = lane >> 4;

  // XCD-aware bijective swizzle (nwg % 8 == 0 for all our launches)
  int bid = (int)blockIdx.x;
  int nwg = (int)gridDim.x;
  if ((nwg & 7) == 0) bid = (bid & 7) * (nwg >> 3) + (bid >> 3);

  const int nbn = N >> 7;
  const int bm = bid / nbn;
  const int bn = bid % nbn;
  const long arow0 = (long)bm * 128;
  const long brow0 = (long)bn * 128;

  f32x4 acc[4][4] = {};

  const int srow = tid >> 3;   // staging row within 32-row group
  const int scol = tid & 7;    // staging 16B slot

  for (int k0 = 0; k0 < K; k0 += 64) {
    if (MODE == 2) {
      // reg-staged A: linear f32 global read, convert, ds_write to XOR'd slot
#pragma unroll
      for (int i = 0; i < 4; ++i) {
        int row = i * 32 + srow;
        int slot = scol ^ (row & 7);
        const float* src = Af + (arow0 + row) * K + k0 + scol * 8;
        f32x4 v0 = *(const f32x4*)src;
        f32x4 v1 = *(const f32x4*)(src + 4);
        u16x8 o;
        o[0] = f2b(v0[0]); o[1] = f2b(v0[1]); o[2] = f2b(v0[2]); o[3] = f2b(v0[3]);
        o[4] = f2b(v1[0]); o[5] = f2b(v1[1]); o[6] = f2b(v1[2]); o[7] = f2b(v1[3]);
        *(u16x8*)(lA + row * 64 + slot * 8) = o;
      }
    } else {
#pragma unroll
      for (int i = 0; i < 4; ++i) {
        int row = i * 32 + srow;
        int kc = scol ^ (row & 7);  // pre-swizzled global source, linear LDS dest
        __builtin_amdgcn_global_load_lds(AS1P(A + (arow0 + row) * K + k0 + kc * 8),
                                         AS3P(lA + i * 2048 + (tid & ~63) * 8), 16, 0, 0);
      }
    }
#pragma unroll
    for (int i = 0; i < 4; ++i) {
      int row = i * 32 + srow;
      int kc = scol ^ (row & 7);
      __builtin_amdgcn_global_load_lds(AS1P(Bt + (brow0 + row) * K + k0 + kc * 8),
                                       AS3P(lB + i * 2048 + (tid & ~63) * 8), 16, 0, 0);
    }
    asm volatile("s_waitcnt vmcnt(0)" ::: "memory");
    __syncthreads();

#pragma unroll
    for (int ks = 0; ks < 2; ++ks) {
      bf16x8 af[4], bfr[4];
#pragma unroll
      for (int m = 0; m < 4; ++m) {
        int row = wm * 64 + m * 16 + lr;
        int off = row * 128 + ks * 64 + lg * 16;
        off ^= (row & 7) << 4;
        af[m] = *(const bf16x8*)((const char*)lA + off);
      }
#pragma unroll
      for (int n = 0; n < 4; ++n) {
        int row = wn * 64 + n * 16 + lr;
        int off = row * 128 + ks * 64 + lg * 16;
        off ^= (row & 7) << 4;
        bfr[n] = *(const bf16x8*)((const char*)lB + off);
      }
#pragma unroll
      for (int m = 0; m < 4; ++m)
#pragma unroll
        for (int n = 0; n < 4; ++n)
          acc[m][n] = MFMA16(af[m], bfr[n], acc[m][n]);
    }
    __syncthreads();
  }

  // epilogue: C/D layout row=(lane>>4)*4+r, col=lane&15
#pragma unroll
  for (int m = 0; m < 4; ++m) {
#pragma unroll
    for (int n = 0; n < 4; ++n) {
      long col = brow0 + wn * 64 + n * 16 + lr;
#pragma unroll
      for (int r = 0; r < 4; ++r) {
        long row = arow0 + wm * 64 + m * 16 + lg * 4 + r;
        float v = acc[m][n][r];
        if (MODE == 1) {
          long idx = row * N + col;
          outf[idx] = v + bias[col] + resid[idx];
        } else {
          outb[row * N + col] = f2b(v * ascale);
        }
      }
    }
  }
}

// ---------------- fused decomposing attention (v5: no barriers at all) ----------------
// grid: 2048 blocks (b2 x h16 x sblk64), block 256 = 4 waves x 16 s-rows.
// All K/V loads are 1 contiguous 1KB segment per instruction (fragment-order buffers,
// L2/L3-resident, 8MB total). P slab wave-private in LDS (pitch 36 u16, 0 conflicts
// measured). NO barriers: waves share nothing -> compiler can software-pipeline the
// fully-unrolled 8-chunk loop (hoist chunk ch+1 loads over chunk ch softmax/PV).
// q pre-scaled by scale*log2e; vfrag pre-scaled by C/Se.
__global__ __launch_bounds__(256) void attn_fused(
    const u16* __restrict__ q,      // [BC][S][D] bf16 (scaled)
    const u16* __restrict__ kfrag,  // [b][h][ch8][c4][tsl2][ks2][512]
    const u16* __restrict__ vfrag,  // [b][h][ch8][c4][dsu4][512] (scaled)
    u16* __restrict__ attn,         // [BC][S][D] bf16
    float* __restrict__ ent) {      // [B][H][S][Se] f32
  const int B = 2, H = 16, S = 4096, Se = 256, D = 1024;
  __shared__ u16 ldsP[4 * 2304];  // per wave: [c:4][s:16][pitch 36]
  const int tid = threadIdx.x;
  const int lane = tid & 63, wid = tid >> 6;
  const int lr = lane & 15, lg = lane >> 4;
  int bid = (int)blockIdx.x;
  bid = (bid & 7) * 256 + (bid >> 3);  // XCD swizzle (2048 blocks)
  const int sblk = bid & 63;
  const int h = (bid >> 6) & 15;
  const int b = bid >> 10;
  const int s0 = sblk * 64 + wid * 16;

  u16* Pw = ldsP + wid * 2304;

  // hoisted Q fragments: A-frag row=lr, k=ks*32+lg*8+e  (q pre-scaled)
  bf16x8 qf[4][2];
#pragma unroll
  for (int c = 0; c < 4; ++c)
#pragma unroll
    for (int ks = 0; ks < 2; ++ks)
      qf[c][ks] = *(const bf16x8*)(q + ((c * B + b) * (long)S + s0 + lr) * D +
                                   h * 64 + ks * 32 + lg * 8);

  const u16* kbh = kfrag + (long)(b * 16 + h) * 65536 + lane * 8;
  const u16* vbh = vfrag + (long)(b * 16 + h) * 65536 + lane * 8;
  float* entp = ent + ((long)(b * H + h) * S + s0 + lg * 4) * Se + lr;

  const float LN2 = 0.69314718056f;

  f32x4 oacc[4][4] = {};  // [c][dh-subtile]

#pragma unroll
  for (int ch = 0; ch < 8; ++ch) {
    // ---- QK^T: every kf load = one contiguous 1KB wave segment
    const u16* kc = kbh + ch * 8192;
    f32x4 sacc[4][2] = {};
#pragma unroll
    for (int c = 0; c < 4; ++c)
#pragma unroll
      for (int tsl = 0; tsl < 2; ++tsl)
#pragma unroll
        for (int ks = 0; ks < 2; ++ks) {
          bf16x8 kf = *(const bf16x8*)(kc + ((c * 4 + tsl * 2 + ks) << 9));
          sacc[c][tsl] = MFMA16(qf[c][ks], kf, sacc[c][tsl]);
        }

    // ---- in-lane component softmax + entropy + P write (no max-sub: |t| small)
#pragma unroll
    for (int tsl = 0; tsl < 2; ++tsl) {
#pragma unroll
      for (int r = 0; r < 4; ++r) {
        float t0 = sacc[0][tsl][r];
        float t1 = sacc[1][tsl][r];
        float t2 = sacc[2][tsl][r];
        float t3 = sacc[3][tsl][r];
        float e0 = __builtin_amdgcn_exp2f(t0);
        float e1 = __builtin_amdgcn_exp2f(t1);
        float e2 = __builtin_amdgcn_exp2f(t2);
        float e3 = __builtin_amdgcn_exp2f(t3);
        float sum = (e0 + e1) + (e2 + e3);
        float inv = __builtin_amdgcn_rcpf(sum);
        float l2s = __builtin_amdgcn_logf(sum);
        float w0 = e0 * inv, w1 = e1 * inv, w2 = e2 * inv, w3 = e3 * inv;
        float entv = (w0 * t0 + w1 * t1 + w2 * t2 + w3 * t3 - l2s) * LN2;
        entp[r * Se + ch * 32 + tsl * 16] = entv;
        int pof = (lg * 4 + r) * 36 + tsl * 16 + lr;
        Pw[0 * 576 + pof] = f2b(w0);
        Pw[1 * 576 + pof] = f2b(w1);
        Pw[2 * 576 + pof] = f2b(w2);
        Pw[3 * 576 + pof] = f2b(w3);
      }
    }

    // ---- PV: every vf load = one contiguous 1KB wave segment
    const u16* vc = vbh + ch * 8192;
#pragma unroll
    for (int c = 0; c < 4; ++c) {
      union { bf16x4 hh[2]; bf16x8 v; } pu;
      pu.hh[0] = *(const bf16x4*)(Pw + c * 576 + lr * 36 + lg * 8);
      pu.hh[1] = *(const bf16x4*)(Pw + c * 576 + lr * 36 + lg * 8 + 4);
      bf16x8 pf = pu.v;
#pragma unroll
      for (int dsu = 0; dsu < 4; ++dsu) {
        bf16x8 vf = *(const bf16x8*)(vc + ((c * 4 + dsu) << 9));
        oacc[c][dsu] = MFMA16(pf, vf, oacc[c][dsu]);
      }
    }
  }

  // ---- epilogue: write attn out bf16
#pragma unroll
  for (int c = 0; c < 4; ++c)
#pragma unroll
    for (int dsu = 0; dsu < 4; ++dsu)
#pragma unroll
      for (int r = 0; r < 4; ++r) {
        int s = s0 + lg * 4 + r;
        attn[((c * B + b) * (long)S + s) * D + h * 64 + dsu * 16 + lr] =
            f2b(oacc[c][dsu][r]);
      }
}

extern "C" void kernel_launch(void* const* d_in, const int* in_sizes, int n_in,
                              void* d_out, int out_size, void* d_ws, size_t ws_size,
                              hipStream_t stream) {
  const float* hs  = (const float*)d_in[0];  // [8,4096,1024]
  const float* ehs = (const float*)d_in[1];  // [8,256,2048]
  const float* Wq  = (const float*)d_in[2];  // [1024,1024]
  const float* Wk  = (const float*)d_in[3];  // [2048,1024]
  const float* Wv  = (const float*)d_in[4];  // [2048,1024]
  const float* Wo  = (const float*)d_in[5];  // [1024,1024]
  const float* bo  = (const float*)d_in[6];  // [1024]
  float* out = (float*)d_out;
  float* ent = out + (size_t)8 * 4096 * 1024;

  char* ws = (char*)d_ws;
  u16* hsb   = (u16*)(ws);              // 67,108,864 B (attn-out buffer, bf16)
  u16* ehsb  = (u16*)(ws + 67108864);   //  8,388,608 B (dead after K/V GEMMs)
  u16* kfrag = (u16*)(ws + 67108864);   //  4,194,304 B (overwrites ehsb after its last use)
  u16* vfrag = (u16*)(ws + 71303168);   //  4,194,304 B
  u16* wqT   = (u16*)(ws + 75497472);   //  2,097,152 B
  u16* wkT   = (u16*)(ws + 77594624);   //  4,194,304 B
  u16* wvT   = (u16*)(ws + 81788928);   //  4,194,304 B
  u16* woT   = (u16*)(ws + 85983232);   //  2,097,152 B
  u16* qb    = (u16*)(ws + 88080384);   // 67,108,864 B
  u16* kb    = (u16*)(ws + 155189248);  //  4,194,304 B
  u16* vtmp  = (u16*)(ws + 159383552);  //  4,194,304 B
  u16* vtb   = (u16*)(ws + 163577856);  //  4,194,304 B  (end: 167,772,160)

  const float QSCALE = 0.125f * 1.44269504f;  // attn.scale * log2(e)

  cvt_f32_bf16<<<512, 256, 0, stream>>>(ehs, ehsb, (8 * 256 * 2048) / 4);
  wtrans<<<1024, 256, 0, stream>>>(Wq, wqT, 1024, 1024);
  wtrans<<<2048, 256, 0, stream>>>(Wk, wkT, 2048, 1024);
  wtrans<<<2048, 256, 0, stream>>>(Wv, wvT, 2048, 1024);
  wtrans<<<1024, 256, 0, stream>>>(Wo, woT, 1024, 1024);
  // q = (hs @ Wq) * scale*log2e   (A = f32 hs, converted during staging)
  gemm_bt<2><<<(32768 / 128) * (1024 / 128), 256, 0, stream>>>(
      nullptr, hs, wqT, qb, nullptr, nullptr, nullptr, 32768, 1024, 1024, QSCALE);
  // k = ehs @ Wk
  gemm_bt<0><<<(2048 / 128) * (1024 / 128), 256, 0, stream>>>(
      ehsb, nullptr, wkT, kb, nullptr, nullptr, nullptr, 2048, 1024, 2048, 1.0f);
  // v = ehs @ Wv
  gemm_bt<0><<<(2048 / 128) * (1024 / 128), 256, 0, stream>>>(
      ehsb, nullptr, wvT, vtmp, nullptr, nullptr, nullptr, 2048, 1024, 2048, 1.0f);
  vtrans<<<2048, 256, 0, stream>>>(vtmp, vtb);   // also scales by C/Se
  kfrag_build<<<1024, 256, 0, stream>>>(kb, kfrag);    // ehsb region now dead -> reuse
  vfrag_build<<<1024, 256, 0, stream>>>(vtb, vfrag);
  // fused component-softmax attention (writes attn into hsb region + entropy to d_out)
  attn_fused<<<2048, 256, 0, stream>>>(qb, kfrag, vfrag, hsb, ent);
  // out = attn @ Wo + bo + hs
  gemm_bt<1><<<(32768 / 128) * (1024 / 128), 256, 0, stream>>>(
      hsb, nullptr, woT, nullptr, out, bo, hs, 32768, 1024, 1024, 1.0f);
}

// Round 6
// 485.133 us; speedup vs baseline: 1.2518x; 1.2518x over previous
//
#include <hip/hip_runtime.h>

typedef unsigned short u16;
typedef __bf16 bf16x4 __attribute__((ext_vector_type(4)));
typedef __bf16 bf16x8 __attribute__((ext_vector_type(8)));
typedef float f32x4 __attribute__((ext_vector_type(4)));
typedef u16 u16x4 __attribute__((ext_vector_type(4)));
typedef u16 u16x8 __attribute__((ext_vector_type(8)));

#define AS1P(p) ((__attribute__((address_space(1))) void*)(unsigned long long)(p))
#define AS3P(p) ((__attribute__((address_space(3))) void*)(unsigned long long)(p))
#define MFMA16(a, b, c) __builtin_amdgcn_mfma_f32_16x16x32_bf16((a), (b), (c), 0, 0, 0)

__device__ __forceinline__ u16 f2b(float x) { return __builtin_bit_cast(u16, (__bf16)x); }
__device__ __forceinline__ float b2f(u16 u) {
  return __builtin_bit_cast(float, (unsigned)u << 16);
}

// ---------------- elementwise f32 -> bf16 ----------------
__global__ __launch_bounds__(256) void cvt_f32_bf16(const float* __restrict__ in,
                                                    u16* __restrict__ out, int n4) {
  int stride = gridDim.x * blockDim.x;
  for (int i = blockIdx.x * blockDim.x + threadIdx.x; i < n4; i += stride) {
    f32x4 v = *(const f32x4*)(in + (long)i * 4);
    u16x4 o;
    o[0] = f2b(v[0]); o[1] = f2b(v[1]); o[2] = f2b(v[2]); o[3] = f2b(v[3]);
    *(u16x4*)(out + (long)i * 4) = o;
  }
}

// ---------------- weight transpose f32[K][N] -> bf16[N][K] ----------------
__global__ __launch_bounds__(256) void wtrans(const float* __restrict__ W,
                                              u16* __restrict__ Wt, int K, int N) {
  __shared__ float tile[32][33];
  int nbk = K >> 5;
  int bk = blockIdx.x % nbk;
  int bn = blockIdx.x / nbk;
  int tx = threadIdx.x & 31, ty = threadIdx.x >> 5;  // 32 x 8
#pragma unroll
  for (int i = 0; i < 32; i += 8)
    tile[ty + i][tx] = W[(long)(bk * 32 + ty + i) * N + bn * 32 + tx];
  __syncthreads();
#pragma unroll
  for (int i = 0; i < 32; i += 8)
    Wt[(long)(bn * 32 + ty + i) * K + bk * 32 + tx] = f2b(tile[tx][ty + i]);
}

// ---------------- v transpose bf16 [8][256][1024] -> [8][1024][256], scaled by C/Se ---
__global__ __launch_bounds__(256) void vtrans(const u16* __restrict__ v, u16* __restrict__ vt) {
  __shared__ u16 tile[32][33];
  int bt = blockIdx.x & 7;          // Se/32
  int bd = (blockIdx.x >> 3) & 31;  // D/32
  int bc = blockIdx.x >> 8;         // 8
  int tx = threadIdx.x & 31, ty = threadIdx.x >> 5;
  const long vb = (long)bc * 256 * 1024;
  const long ob = (long)bc * 1024 * 256;
  const float RS = 1.0f / 64.0f;  // C/Se (exact pow2: no rounding)
#pragma unroll
  for (int i = 0; i < 32; i += 8)
    tile[ty + i][tx] = v[vb + (long)(bt * 32 + ty + i) * 1024 + bd * 32 + tx];
  __syncthreads();
#pragma unroll
  for (int i = 0; i < 32; i += 8)
    vt[ob + (long)(bd * 32 + ty + i) * 256 + bt * 32 + tx] =
        f2b(b2f(tile[tx][ty + i]) * RS);
}

// ---------------- K fragmentizer: kb[BC][Se][D] -> MFMA B-frag order -------------------
// frag id wv = ((((b*16+h)*8+ch)*4+c)*2+tsl)*2+ks ; element: lane*8 (16B/lane, coalesced)
__global__ __launch_bounds__(256) void kfrag_build(const u16* __restrict__ kb,
                                                   u16* __restrict__ kfrag) {
  int wv = ((int)blockIdx.x << 2) + (threadIdx.x >> 6);  // 0..4095
  int lane = threadIdx.x & 63, lr = lane & 15, lg = lane >> 4;
  int ks = wv & 1, tsl = (wv >> 1) & 1, c = (wv >> 2) & 3;
  int ch = (wv >> 4) & 7, h = (wv >> 7) & 15, b = (wv >> 11) & 1;
  const u16* src = kb + ((long)(c * 2 + b) * 256 + ch * 32 + tsl * 16 + lr) * 1024 +
                   h * 64 + ks * 32 + lg * 8;
  *(bf16x8*)(kfrag + (long)wv * 512 + lane * 8) = *(const bf16x8*)src;
}

// ---------------- V fragmentizer: vtb[BC][D][Se] -> MFMA B-frag order ------------------
// frag id wv = ((((b*16+h)*8+ch)*4+c)*4+dsu
__global__ __launch_bounds__(256) void vfrag_build(const u16* __restrict__ vtb,
                                                   u16* __restrict__ vfrag) {
  int wv = ((int)blockIdx.x << 2) + (threadIdx.x >> 6);  // 0..4095
  int lane = threadIdx.x & 63, lr = lane & 15, lg = lane >> 4;
  int dsu = wv & 3, c = (wv >> 2) & 3;
  int ch = (wv >> 4) & 7, h = (wv >> 7) & 15, b = (wv >> 11) & 1;
  const u16* src = vtb + ((long)(c * 2 + b) * 1024 + h * 64 + dsu * 16 + lr) * 256 +
                   ch * 32 + lg * 8;
  *(bf16x8*)(vfrag + (long)wv * 512 + lane * 8) = *(const bf16x8*)src;
}

// ---------------- GEMM: C[M,N] = A[M,K] @ Bt[N,K]^T (bf16 in, MFMA 16x16x32) ----------
// MODE 0: A bf16; write bf16 C*ascale.
// MODE 1: A bf16; write f32 C + bias[n] + resid[m*N+n].
// MODE 2: A f32 (converted to bf16 during reg-staging); write bf16 C*ascale.
template <int MODE>
__global__ __launch_bounds__(256) void gemm_bt(
    const u16* __restrict__ A, const float* __restrict__ Af,
    const u16* __restrict__ Bt,
    u16* __restrict__ outb, float* __restrict__ outf,
    const float* __restrict__ bias, const float* __restrict__ resid,
    int M, int N, int K, float ascale) {
  __shared__ u16 lA[128 * 64];  // [row][slot]; LDS slot s holds data k-slot s^(row&7)
  __shared__ u16 lB[128 * 64];
  const int tid = threadIdx.x;
  const int lane = tid & 63;
  const int wid = tid >> 6;
  const int wm = wid >> 1, wn = wid & 1;
  const int lr = lane & 15, lg = lane >> 4;

  // XCD-aware bijective swizzle (nwg % 8 == 0 for all our launches)
  int bid = (int)blockIdx.x;
  int nwg = (int)gridDim.x;
  if ((nwg & 7) == 0) bid = (bid & 7) * (nwg >> 3) + (bid >> 3);

  const int nbn = N >> 7;
  const int bm = bid / nbn;
  const int bn = bid % nbn;
  const long arow0 = (long)bm * 128;
  const long brow0 = (long)bn * 128;

  f32x4 acc[4][4] = {};

  const int srow = tid >> 3;   // staging row within 32-row group
  const int scol = tid & 7;    // staging 16B slot

  for (int k0 = 0; k0 < K; k0 += 64) {
    if (MODE == 2) {
      // reg-staged A: linear f32 global read, convert, ds_write to XOR'd slot
#pragma unroll
      for (int i = 0; i < 4; ++i) {
        int row = i * 32 + srow;
        int slot = scol ^ (row & 7);
        const float* src = Af + (arow0 + row) * K + k0 + scol * 8;
        f32x4 v0 = *(const f32x4*)src;
        f32x4 v1 = *(const f32x4*)(src + 4);
        u16x8 o;
        o[0] = f2b(v0[0]); o[1] = f2b(v0[1]); o[2] = f2b(v0[2]); o[3] = f2b(v0[3]);
        o[4] = f2b(v1[0]); o[5] = f2b(v1[1]); o[6] = f2b(v1[2]); o[7] = f2b(v1[3]);
        *(u16x8*)(lA + row * 64 + slot * 8) = o;
      }
    } else {
#pragma unroll
      for (int i = 0; i < 4; ++i) {
        int row = i * 32 + srow;
        int kc = scol ^ (row & 7);  // pre-swizzled global source, linear LDS dest
        __builtin_amdgcn_global_load_lds(AS1P(A + (arow0 + row) * K + k0 + kc * 8),
                                         AS3P(lA + i * 2048 + (tid & ~63) * 8), 16, 0, 0);
      }
    }
#pragma unroll
    for (int i = 0; i < 4; ++i) {
      int row = i * 32 + srow;
      int kc = scol ^ (row & 7);
      __builtin_amdgcn_global_load_lds(AS1P(Bt + (brow0 + row) * K + k0 + kc * 8),
                                       AS3P(lB + i * 2048 + (tid & ~63) * 8), 16, 0, 0);
    }
    asm volatile("s_waitcnt vmcnt(0)" ::: "memory");
    __syncthreads();

#pragma unroll
    for (int ks = 0; ks < 2; ++ks) {
      bf16x8 af[4], bfr[4];
#pragma unroll
      for (int m = 0; m < 4; ++m) {
        int row = wm * 64 + m * 16 + lr;
        int off = row * 128 + ks * 64 + lg * 16;
        off ^= (row & 7) << 4;
        af[m] = *(const bf16x8*)((const char*)lA + off);
      }
#pragma unroll
      for (int n = 0; n < 4; ++n) {
        int row = wn * 64 + n * 16 + lr;
        int off = row * 128 + ks * 64 + lg * 16;
        off ^= (row & 7) << 4;
        bfr[n] = *(const bf16x8*)((const char*)lB + off);
      }
#pragma unroll
      for (int m = 0; m < 4; ++m)
#pragma unroll
        for (int n = 0; n < 4; ++n)
          acc[m][n] = MFMA16(af[m], bfr[n], acc[m][n]);
    }
    __syncthreads();
  }

  // epilogue: C/D layout row=(lane>>4)*4+r, col=lane&15
#pragma unroll
  for (int m = 0; m < 4; ++m) {
#pragma unroll
    for (int n = 0; n < 4; ++n) {
      long col = brow0 + wn * 64 + n * 16 + lr;
#pragma unroll
      for (int r = 0; r < 4; ++r) {
        long row = arow0 + wm * 64 + m * 16 + lg * 4 + r;
        float v = acc[m][n][r];
        if (MODE == 1) {
          long idx = row * N + col;
          outf[idx] = v + bias[col] + resid[idx];
        } else {
          outb[row * N + col] = f2b(v * ascale);
        }
      }
    }
  }
}

// ---------------- fused decomposing attention (v6: register-pipelined) ----------------
// grid: 2048 blocks (b2 x h16 x sblk64), block 256 = 4 waves x 16 s-rows.
// Per iteration ch: ALL 16 vf(ch) loads + ALL 16 kf(ch+1) loads are issued up-front,
// pinned by sched_barrier(0) so the compiler cannot sink them to their uses. kf is a
// loop-carried register double-buffer (full unroll -> SSA renaming, static indices).
// 1 wave/SIMD by design (launch_bounds min-waves=1): latency hidden by ILP, not TLP.
// q pre-scaled by scale*log2e; vfrag pre-scaled by C/Se. P slab wave-private in LDS.
__global__ __launch_bounds__(256, 1) void attn_fused(
    const u16* __restrict__ q,      // [BC][S][D] bf16 (scaled)
    const u16* __restrict__ kfrag,  // [b][h][ch8][c4][tsl2][ks2][512]
    const u16* __restrict__ vfrag,  // [b][h][ch8][c4][dsu4][512] (scaled)
    u16* __restrict__ attn,         // [BC][S][D] bf16
    float* __restrict__ ent) {      // [B][H][S][Se] f32
  const int B = 2, H = 16, S = 4096, Se = 256, D = 1024;
  __shared__ u16 ldsP[4 * 2304];  // per wave: [c:4][s:16][pitch 36]
  const int tid = threadIdx.x;
  const int lane = tid & 63, wid = tid >> 6;
  const int lr = lane & 15, lg = lane >> 4;
  int bid = (int)blockIdx.x;
  bid = (bid & 7) * 256 + (bid >> 3);  // XCD swizzle (2048 blocks)
  const int sblk = bid & 63;
  const int h = (bid >> 6) & 15;
  const int b = bid >> 10;
  const int s0 = sblk * 64 + wid * 16;

  u16* Pw = ldsP + wid * 2304;

  // hoisted Q fragments: A-frag row=lr, k=ks*32+lg*8+e  (q pre-scaled)
  bf16x8 qf[4][2];
#pragma unroll
  for (int c = 0; c < 4; ++c)
#pragma unroll
    for (int ks = 0; ks < 2; ++ks)
      qf[c][ks] = *(const bf16x8*)(q + ((c * B + b) * (long)S + s0 + lr) * D +
                                   h * 64 + ks * 32 + lg * 8);

  const u16* kbh = kfrag + (long)(b * 16 + h) * 65536 + lane * 8;
  const u16* vbh = vfrag + (long)(b * 16 + h) * 65536 + lane * 8;
  float* entp = ent + ((long)(b * H + h) * S + s0 + lg * 4) * Se + lr;

  const float LN2 = 0.69314718056f;

  f32x4 oacc[4][4] = {};  // [c][dh-subtile]

  // prologue: kf for chunk 0
  bf16x8 kf[16];
#pragma unroll
  for (int i = 0; i < 16; ++i) kf[i] = *(const bf16x8*)(kbh + (i << 9));

#pragma unroll
  for (int ch = 0; ch < 8; ++ch) {
    // ---- issue ALL of this chunk's V loads and next chunk's K loads NOW
    const u16* vc = vbh + ch * 8192;
    bf16x8 vf[16];
#pragma unroll
    for (int i = 0; i < 16; ++i) vf[i] = *(const bf16x8*)(vc + (i << 9));
    bf16x8 kfn[16];
    if (ch < 7) {
      const u16* kn = kbh + (ch + 1) * 8192;
#pragma unroll
      for (int i = 0; i < 16; ++i) kfn[i] = *(const bf16x8*)(kn + (i << 9));
    }
    __builtin_amdgcn_sched_barrier(0);  // loads stay issued above the compute

    // ---- QK^T from current kf registers (frag idx = c*4 + tsl*2 + ks)
    f32x4 sacc[4][2] = {};
#pragma unroll
    for (int c = 0; c < 4; ++c)
#pragma unroll
      for (int tsl = 0; tsl < 2; ++tsl)
#pragma unroll
        for (int ks = 0; ks < 2; ++ks)
          sacc[c][tsl] = MFMA16(qf[c][ks], kf[c * 4 + tsl * 2 + ks], sacc[c][tsl]);

    // ---- in-lane component softmax + entropy + P write (no max-sub: |t| small)
#pragma unroll
    for (int tsl = 0; tsl < 2; ++tsl) {
#pragma unroll
      for (int r = 0; r < 4; ++r) {
        float t0 = sacc[0][tsl][r];
        float t1 = sacc[1][tsl][r];
        float t2 = sacc[2][tsl][r];
        float t3 = sacc[3][tsl][r];
        float e0 = __builtin_amdgcn_exp2f(t0);
        float e1 = __builtin_amdgcn_exp2f(t1);
        float e2 = __builtin_amdgcn_exp2f(t2);
        float e3 = __builtin_amdgcn_exp2f(t3);
        float sum = (e0 + e1) + (e2 + e3);
        float inv = __builtin_amdgcn_rcpf(sum);
        float l2s = __builtin_amdgcn_logf(sum);
        float w0 = e0 * inv, w1 = e1 * inv, w2 = e2 * inv, w3 = e3 * inv;
        float entv = (w0 * t0 + w1 * t1 + w2 * t2 + w3 * t3 - l2s) * LN2;
        __builtin_nontemporal_store(entv, entp + r * Se + ch * 32 + tsl * 16);
        int pof = (lg * 4 + r) * 36 + tsl * 16 + lr;
        Pw[0 * 576 + pof] = f2b(w0);
        Pw[1 * 576 + pof] = f2b(w1);
        Pw[2 * 576 + pof] = f2b(w2);
        Pw[3 * 576 + pof] = f2b(w3);
      }
    }

    // ---- PV from vf registers (arrived during QK^T+softmax)
#pragma unroll
    for (int c = 0; c < 4; ++c) {
      union { bf16x4 hh[2]; bf16x8 v; } pu;
      pu.hh[0] = *(const bf16x4*)(Pw + c * 576 + lr * 36 + lg * 8);
      pu.hh[1] = *(const bf16x4*)(Pw + c * 576 + lr * 36 + lg * 8 + 4);
      bf16x8 pf = pu.v;
#pragma unroll
      for (int dsu = 0; dsu < 4; ++dsu)
        oacc[c][dsu] = MFMA16(pf, vf[c * 4 + dsu], oacc[c][dsu]);
    }

    // ---- rotate K register double-buffer (SSA rename under full unroll)
    if (ch < 7) {
#pragma unroll
      for (int i = 0; i < 16; ++i) kf[i] = kfn[i];
    }
  }

  // ---- epilogue: write attn out bf16
#pragma unroll
  for (int c = 0; c < 4; ++c)
#pragma unroll
    for (int dsu = 0; dsu < 4; ++dsu)
#pragma unroll
      for (int r = 0; r < 4; ++r) {
        int s = s0 + lg * 4 + r;
        attn[((c * B + b) * (long)S + s) * D + h * 64 + dsu * 16 + lr] =
            f2b(oacc[c][dsu][r]);
      }
}

extern "C" void kernel_launch(void* const* d_in, const int* in_sizes, int n_in,
                              void* d_out, int out_size, void* d_ws, size_t ws_size,
                              hipStream_t stream) {
  const float* hs  = (const float*)d_in[0];  // [8,4096,1024]
  const float* ehs = (const float*)d_in[1];  // [8,256,2048]
  const float* Wq  = (const float*)d_in[2];  // [1024,1024]
  const float* Wk  = (const float*)d_in[3];  // [2048,1024]
  const float* Wv  = (const float*)d_in[4];  // [2048,1024]
  const float* Wo  = (const float*)d_in[5];  // [1024,1024]
  const float* bo  = (const float*)d_in[6];  // [1024]
  float* out = (float*)d_out;
  float* ent = out + (size_t)8 * 4096 * 1024;

  char* ws = (char*)d_ws;
  u16* hsb   = (u16*)(ws);              // 67,108,864 B (attn-out buffer, bf16)
  u16* ehsb  = (u16*)(ws + 67108864);   //  8,388,608 B (dead after K/V GEMMs)
  u16* kfrag = (u16*)(ws + 67108864);   //  4,194,304 B (overwrites ehsb after its last use)
  u16* vfrag = (u16*)(ws + 71303168);   //  4,194,304 B
  u16* wqT   = (u16*)(ws + 75497472);   //  2,097,152 B
  u16* wkT   = (u16*)(ws + 77594624);   //  4,194,304 B
  u16* wvT   = (u16*)(ws + 81788928);   //  4,194,304 B
  u16* woT   = (u16*)(ws + 85983232);   //  2,097,152 B
  u16* qb    = (u16*)(ws + 88080384);   // 67,108,864 B
  u16* kb    = (u16*)(ws + 155189248);  //  4,194,304 B
  u16* vtmp  = (u16*)(ws + 159383552);  //  4,194,304 B
  u16* vtb   = (u16*)(ws + 163577856);  //  4,194,304 B  (end: 167,772,160)

  const float QSCALE = 0.125f * 1.44269504f;  // attn.scale * log2(e)

  cvt_f32_bf16<<<512, 256, 0, stream>>>(ehs, ehsb, (8 * 256 * 2048) / 4);
  wtrans<<<1024, 256, 0, stream>>>(Wq, wqT, 1024, 1024);
  wtrans<<<2048, 256, 0, stream>>>(Wk, wkT, 2048, 1024);
  wtrans<<<2048, 256, 0, stream>>>(Wv, wvT, 2048, 1024);
  wtrans<<<1024, 256, 0, stream>>>(Wo, woT, 1024, 1024);
  // q = (hs @ Wq) * scale*log2e   (A = f32 hs, converted during staging)
  gemm_bt<2><<<(32768 / 128) * (1024 / 128), 256, 0, stream>>>(
      nullptr, hs, wqT, qb, nullptr, nullptr, nullptr, 32768, 1024, 1024, QSCALE);
  // k = ehs @ Wk
  gemm_bt<0><<<(2048 / 128) * (1024 / 128), 256, 0, stream>>>(
      ehsb, nullptr, wkT, kb, nullptr, nullptr, nullptr, 2048, 1024, 2048, 1.0f);
  // v = ehs @ Wv
  gemm_bt<0><<<(2048 / 128) * (1024 / 128), 256, 0, stream>>>(
      ehsb, nullptr, wvT, vtmp, nullptr, nullptr, nullptr, 2048, 1024, 2048, 1.0f);
  vtrans<<<2048, 256, 0, stream>>>(vtmp, vtb);   // also scales by C/Se
  kfrag_build<<<1024, 256, 0, stream>>>(kb, kfrag);    // ehsb region now dead -> reuse
  vfrag_build<<<1024, 256, 0, stream>>>(vtb, vfrag);
  // fused component-softmax attention (writes attn into hsb region + entropy to d_out)
  attn_fused<<<2048, 256, 0, stream>>>(qb, kfrag, vfrag, hsb, ent);
  // out = attn @ Wo + bo + hs
  gemm_bt<1><<<(32768 / 128) * (1024 / 128), 256, 0, stream>>>(
      hsb, nullptr, woT, nullptr, out, bo, hs, 32768, 1024, 1024, 1.0f);
}

// Round 7
// 412.753 us; speedup vs baseline: 1.4713x; 1.1754x over previous
//
#include <hip/hip_runtime.h>

typedef unsigned short u16;
typedef __bf16 bf16x4 __attribute__((ext_vector_type(4)));
typedef __bf16 bf16x8 __attribute__((ext_vector_type(8)));
typedef float f32x4 __attribute__((ext_vector_type(4)));
typedef u16 u16x4 __attribute__((ext_vector_type(4)));
typedef u16 u16x8 __attribute__((ext_vector_type(8)));

#define AS1P(p) ((__attribute__((address_space(1))) void*)(unsigned long long)(p))
#define AS3P(p) ((__attribute__((address_space(3))) void*)(unsigned long long)(p))
#define MFMA16(a, b, c) __builtin_amdgcn_mfma_f32_16x16x32_bf16((a), (b), (c), 0, 0, 0)

__device__ __forceinline__ u16 f2b(float x) { return __builtin_bit_cast(u16, (__bf16)x); }
__device__ __forceinline__ float b2f(u16 u) {
  return __builtin_bit_cast(float, (unsigned)u << 16);
}

// ---------------- elementwise f32 -> bf16 ----------------
__global__ __launch_bounds__(256) void cvt_f32_bf16(const float* __restrict__ in,
                                                    u16* __restrict__ out, int n4) {
  int stride = gridDim.x * blockDim.x;
  for (int i = blockIdx.x * blockDim.x + threadIdx.x; i < n4; i += stride) {
    f32x4 v = *(const f32x4*)(in + (long)i * 4);
    u16x4 o;
    o[0] = f2b(v[0]); o[1] = f2b(v[1]); o[2] = f2b(v[2]); o[3] = f2b(v[3]);
    *(u16x4*)(out + (long)i * 4) = o;
  }
}

// ---------------- weight transpose f32[K][N] -> bf16[N][K] ----------------
__global__ __launch_bounds__(256) void wtrans(const float* __restrict__ W,
                                              u16* __restrict__ Wt, int K, int N) {
  __shared__ float tile[32][33];
  int nbk = K >> 5;
  int bk = blockIdx.x % nbk;
  int bn = blockIdx.x / nbk;
  int tx = threadIdx.x & 31, ty = threadIdx.x >> 5;  // 32 x 8
#pragma unroll
  for (int i = 0; i < 32; i += 8)
    tile[ty + i][tx] = W[(long)(bk * 32 + ty + i) * N + bn * 32 + tx];
  __syncthreads();
#pragma unroll
  for (int i = 0; i < 32; i += 8)
    Wt[(long)(bn * 32 + ty + i) * K + bk * 32 + tx] = f2b(tile[tx][ty + i]);
}

// ---------------- v transpose: kvb v-half [8][256][2048(+1024)] -> [8][1024][256] ------
// also scales by C/Se (exact pow2)
__global__ __launch_bounds__(256) void vtrans(const u16* __restrict__ kvb,
                                              u16* __restrict__ vt) {
  __shared__ u16 tile[32][33];
  int bt = blockIdx.x & 7;          // Se/32
  int bd = (blockIdx.x >> 3) & 31;  // D/32
  int bc = blockIdx.x >> 8;         // 8
  int tx = threadIdx.x & 31, ty = threadIdx.x >> 5;
  const long ob = (long)bc * 1024 * 256;
  const float RS = 1.0f / 64.0f;  // C/Se
#pragma unroll
  for (int i = 0; i < 32; i += 8)
    tile[ty + i][tx] =
        kvb[((long)bc * 256 + bt * 32 + ty + i) * 2048 + 1024 + bd * 32 + tx];
  __syncthreads();
#pragma unroll
  for (int i = 0; i < 32; i += 8)
    vt[ob + (long)(bd * 32 + ty + i) * 256 + bt * 32 + tx] =
        f2b(b2f(tile[tx][ty + i]) * RS);
}

// ---------------- K fragmentizer: kvb k-half [BC][Se][2048] -> MFMA B-frag order -------
// frag id wv = ((((b*16+h)*8+ch)*4+c)*2+tsl)*2+ks ; element: lane*8 (16B/lane, coalesced)
__global__ __launch_bounds__(256) void kfrag_build(const u16* __restrict__ kvb,
                                                   u16* __restrict__ kfrag) {
  int wv = ((int)blockIdx.x << 2) + (threadIdx.x >> 6);  // 0..4095
  int lane = threadIdx.x & 63, lr = lane & 15, lg = lane >> 4;
  int ks = wv & 1, tsl = (wv >> 1) & 1, c = (wv >> 2) & 3;
  int ch = (wv >> 4) & 7, h = (wv >> 7) & 15, b = (wv >> 11) & 1;
  const u16* src = kvb + ((long)(c * 2 + b) * 256 + ch * 32 + tsl * 16 + lr) * 2048 +
                   h * 64 + ks * 32 + lg * 8;
  *(bf16x8*)(kfrag + (long)wv * 512 + lane * 8) = *(const bf16x8*)src;
}

// ---------------- V fragmentizer: vtb[BC][D][Se] -> MFMA B-frag order ------------------
// frag id wv = ((((b*16+h)*8+ch)*4+c)*4+dsu
__global__ __launch_bounds__(256) void vfrag_build(const u16* __restrict__ vtb,
                                                   u16* __restrict__ vfrag) {
  int wv = ((int)blockIdx.x << 2) + (threadIdx.x >> 6);  // 0..4095
  int lane = threadIdx.x & 63, lr = lane & 15, lg = lane >> 4;
  int dsu = wv & 3, c = (wv >> 2) & 3;
  int ch = (wv >> 4) & 7, h = (wv >> 7) & 15, b = (wv >> 11) & 1;
  const u16* src = vtb + ((long)(c * 2 + b) * 1024 + h * 64 + dsu * 16 + lr) * 256 +
                   ch * 32 + lg * 8;
  *(bf16x8*)(vfrag + (long)wv * 512 + lane * 8) = *(const bf16x8*)src;
}

// ---------------- GEMM 128^2 (proven): C[M,N] = A[M,K] @ Bt[N,K]^T ---------------------
__global__ __launch_bounds__(256) void gemm_bt(
    const u16* __restrict__ A, const u16* __restrict__ Bt,
    u16* __restrict__ outb, int M, int N, int K, float ascale) {
  __shared__ u16 lA[128 * 64];  // [row][slot]; LDS slot s holds data k-slot s^(row&7)
  __shared__ u16 lB[128 * 64];
  const int tid = threadIdx.x;
  const int lane = tid & 63;
  const int wid = tid >> 6;
  const int wm = wid >> 1, wn = wid & 1;
  const int lr = lane & 15, lg = lane >> 4;

  int bid = (int)blockIdx.x;
  int nwg = (int)gridDim.x;
  if ((nwg & 7) == 0) bid = (bid & 7) * (nwg >> 3) + (bid >> 3);

  const int nbn = N >> 7;
  const int bm = bid / nbn;
  const int bn = bid % nbn;
  const long arow0 = (long)bm * 128;
  const long brow0 = (long)bn * 128;

  f32x4 acc[4][4] = {};

  const int srow = tid >> 3;
  const int scol = tid & 7;

  for (int k0 = 0; k0 < K; k0 += 64) {
#pragma unroll
    for (int i = 0; i < 4; ++i) {
      int row = i * 32 + srow;
      int kc = scol ^ (row & 7);
      __builtin_amdgcn_global_load_lds(AS1P(A + (arow0 + row) * K + k0 + kc * 8),
                                       AS3P(lA + i * 2048 + (tid & ~63) * 8), 16, 0, 0);
    }
#pragma unroll
    for (int i = 0; i < 4; ++i) {
      int row = i * 32 + srow;
      int kc = scol ^ (row & 7);
      __builtin_amdgcn_global_load_lds(AS1P(Bt + (brow0 + row) * K + k0 + kc * 8),
                                       AS3P(lB + i * 2048 + (tid & ~63) * 8), 16, 0, 0);
    }
    asm volatile("s_waitcnt vmcnt(0)" ::: "memory");
    __syncthreads();

#pragma unroll
    for (int ks = 0; ks < 2; ++ks) {
      bf16x8 af[4], bfr[4];
#pragma unroll
      for (int m = 0; m < 4; ++m) {
        int row = wm * 64 + m * 16 + lr;
        int off = row * 128 + ks * 64 + lg * 16;
        off ^= (row & 7) << 4;
        af[m] = *(const bf16x8*)((const char*)lA + off);
      }
#pragma unroll
      for (int n = 0; n < 4; ++n) {
        int row = wn * 64 + n * 16 + lr;
        int off = row * 128 + ks * 64 + lg * 16;
        off ^= (row & 7) << 4;
        bfr[n] = *(const bf16x8*)((const char*)lB + off);
      }
#pragma unroll
      for (int m = 0; m < 4; ++m)
#pragma unroll
        for (int n = 0; n < 4; ++n)
          acc[m][n] = MFMA16(af[m], bfr[n], acc[m][n]);
    }
    __syncthreads();
  }

#pragma unroll
  for (int m = 0; m < 4; ++m)
#pragma unroll
    for (int n = 0; n < 4; ++n) {
      long col = brow0 + wn * 64 + n * 16 + lr;
#pragma unroll
      for (int r = 0; r < 4; ++r) {
        long row = arow0 + wm * 64 + m * 16 + lg * 4 + r;
        outb[row * N + col] = f2b(acc[m][n][r] * ascale);
      }
    }
}

// ---------------- GEMM 256^2 stage-ahead (T3-minimum): C = A @ Bt^T --------------------
// 512 threads = 8 waves (2M x 4N); per-wave C = 128x64. BK=64. Double-buffered 128KB LDS.
// Pipeline: STAGE(t+1 -> other buf) issued BEFORE compute(t); single vmcnt(0)+barrier
// per K-step so stage latency hides under ds_read+MFMA of the current tile.
// MODE 0: write bf16 C*ascale.  MODE 1: write f32 C + bias[n] + resid[m*N+n].
template <int MODE>
__global__ __launch_bounds__(512, 2) void gemm256(
    const u16* __restrict__ A, const u16* __restrict__ Bt,
    u16* __restrict__ outb, float* __restrict__ outf,
    const float* __restrict__ bias, const float* __restrict__ resid,
    int M, int N, int K, float ascale) {
  __shared__ u16 lds[2][2][256 * 64];  // [buf][A=0/B=1][row*64 + slot*8 + e]
  const int tid = threadIdx.x;
  const int lane = tid & 63;
  const int wid = tid >> 6;      // 0..7
  const int wm = wid >> 2;       // 0..1
  const int wn = wid & 3;        // 0..3
  const int lr = lane & 15, lg = lane >> 4;

  int bid = (int)blockIdx.x;
  int nwg = (int)gridDim.x;
  bid = (bid & 7) * (nwg >> 3) + (bid >> 3);  // nwg % 8 == 0 for all our launches

  const int nbn = N >> 8;
  const int bm = bid / nbn;
  const int bn = bid % nbn;
  const long arow0 = (long)bm * 256;
  const long brow0 = (long)bn * 256;

  f32x4 acc[8][4] = {};

  const int srow = tid >> 3;  // 0..63
  const int scol = tid & 7;
  const int nt = K >> 6;

#define STAGE256(bf, t)                                                                \
  do {                                                                                 \
    int k0_ = (t) << 6;                                                                \
    _Pragma("unroll") for (int i = 0; i < 4; ++i) {                                    \
      int row = i * 64 + srow;                                                         \
      int kc = scol ^ (row & 7);                                                       \
      __builtin_amdgcn_global_load_lds(AS1P(A + (arow0 + row) * K + k0_ + kc * 8),     \
                                       AS3P(&lds[bf][0][0] + i * 4096 + (tid & ~63) * 8), \
                                       16, 0, 0);                                      \
    }                                                                                  \
    _Pragma("unroll") for (int i = 0; i < 4; ++i) {                                    \
      int row = i * 64 + srow;                                                         \
      int kc = scol ^ (row & 7);                                                       \
      __builtin_amdgcn_global_load_lds(AS1P(Bt + (brow0 + row) * K + k0_ + kc * 8),    \
                                       AS3P(&lds[bf][1][0] + i * 4096 + (tid & ~63) * 8), \
                                       16, 0, 0);                                      \
    }                                                                                  \
  } while (0)

#define COMPUTE256(bf)                                                                 \
  do {                                                                                 \
    _Pragma("unroll") for (int ks = 0; ks < 2; ++ks) {                                 \
      bf16x8 af[8], bfr[4];                                                            \
      _Pragma("unroll") for (int m = 0; m < 8; ++m) {                                  \
        int row = wm * 128 + m * 16 + lr;                                              \
        int off = row * 128 + ks * 64 + lg * 16;                                       \
        off ^= (row & 7) << 4;                                                         \
        af[m] = *(const bf16x8*)((const char*)&lds[bf][0][0] + off);                   \
      }                                                                                \
      _Pragma("unroll") for (int n = 0; n < 4; ++n) {                                  \
        int row = wn * 64 + n * 16 + lr;                                               \
        int off = row * 128 + ks * 64 + lg * 16;                                       \
        off ^= (row & 7) << 4;                                                         \
        bfr[n] = *(const bf16x8*)((const char*)&lds[bf][1][0] + off);                  \
      }                                                                                \
      _Pragma("unroll") for (int m = 0; m < 8; ++m)                                    \
          _Pragma("unroll") for (int n = 0; n < 4; ++n)                                \
              acc[m][n] = MFMA16(af[m], bfr[n], acc[m][n]);                            \
    }                                                                                  \
  } while (0)

  STAGE256(0, 0);
  asm volatile("s_waitcnt vmcnt(0)" ::: "memory");
  __syncthreads();
  int cur = 0;
  for (int t = 0; t < nt - 1; ++t) {
    STAGE256(cur ^ 1, t + 1);  // issue next-tile loads first: latency hides under compute
    COMPUTE256(cur);
    asm volatile("s_waitcnt vmcnt(0)" ::: "memory");
    __syncthreads();
    cur ^= 1;
  }
  COMPUTE256(cur);

  // epilogue: C/D layout row=(lane>>4)*4+r, col=lane&15
#pragma unroll
  for (int m = 0; m < 8; ++m)
#pragma unroll
    for (int n = 0; n < 4; ++n) {
      long col = brow0 + wn * 64 + n * 16 + lr;
#pragma unroll
      for (int r = 0; r < 4; ++r) {
        long row = arow0 + wm * 128 + m * 16 + lg * 4 + r;
        float v = acc[m][n][r];
        if (MODE == 1) {
          long idx = row * N + col;
          outf[idx] = v + bias[col] + resid[idx];
        } else {
          outb[row * N + col] = f2b(v * ascale);
        }
      }
    }
#undef STAGE256
#undef COMPUTE256
}

// ---------------- fused decomposing attention (v6: register-pipelined, unchanged) -----
__global__ __launch_bounds__(256, 1) void attn_fused(
    const u16* __restrict__ q,      // [BC][S][D] bf16 (scaled)
    const u16* __restrict__ kfrag,  // [b][h][ch8][c4][tsl2][ks2][512]
    const u16* __restrict__ vfrag,  // [b][h][ch8][c4][dsu4][512] (scaled)
    u16* __restrict__ attn,         // [BC][S][D] bf16
    float* __restrict__ ent) {      // [B][H][S][Se] f32
  const int B = 2, H = 16, S = 4096, Se = 256, D = 1024;
  __shared__ u16 ldsP[4 * 2304];  // per wave: [c:4][s:16][pitch 36]
  const int tid = threadIdx.x;
  const int lane = tid & 63, wid = tid >> 6;
  const int lr = lane & 15, lg = lane >> 4;
  int bid = (int)blockIdx.x;
  bid = (bid & 7) * 256 + (bid >> 3);  // XCD swizzle (2048 blocks)
  const int sblk = bid & 63;
  const int h = (bid >> 6) & 15;
  const int b = bid >> 10;
  const int s0 = sblk * 64 + wid * 16;

  u16* Pw = ldsP + wid * 2304;

  bf16x8 qf[4][2];
#pragma unroll
  for (int c = 0; c < 4; ++c)
#pragma unroll
    for (int ks = 0; ks < 2; ++ks)
      qf[c][ks] = *(const bf16x8*)(q + ((c * B + b) * (long)S + s0 + lr) * D +
                                   h * 64 + ks * 32 + lg * 8);

  const u16* kbh = kfrag + (long)(b * 16 + h) * 65536 + lane * 8;
  const u16* vbh = vfrag + (long)(b * 16 + h) * 65536 + lane * 8;
  float* entp = ent + ((long)(b * H + h) * S + s0 + lg * 4) * Se + lr;

  const float LN2 = 0.69314718056f;

  f32x4 oacc[4][4] = {};

  bf16x8 kf[16];
#pragma unroll
  for (int i = 0; i < 16; ++i) kf[i] = *(const bf16x8*)(kbh + (i << 9));

#pragma unroll
  for (int ch = 0; ch < 8; ++ch) {
    const u16* vc = vbh + ch * 8192;
    bf16x8 vf[16];
#pragma unroll
    for (int i = 0; i < 16; ++i) vf[i] = *(const bf16x8*)(vc + (i << 9));
    bf16x8 kfn[16];
    if (ch < 7) {
      const u16* kn = kbh + (ch + 1) * 8192;
#pragma unroll
      for (int i = 0; i < 16; ++i) kfn[i] = *(const bf16x8*)(kn + (i << 9));
    }
    __builtin_amdgcn_sched_barrier(0);  // loads stay issued above the compute

    f32x4 sacc[4][2] = {};
#pragma unroll
    for (int c = 0; c < 4; ++c)
#pragma unroll
      for (int tsl = 0; tsl < 2; ++tsl)
#pragma unroll
        for (int ks = 0; ks < 2; ++ks)
          sacc[c][tsl] = MFMA16(qf[c][ks], kf[c * 4 + tsl * 2 + ks], sacc[c][tsl]);

#pragma unroll
    for (int tsl = 0; tsl < 2; ++tsl) {
#pragma unroll
      for (int r = 0; r < 4; ++r) {
        float t0 = sacc[0][tsl][r];
        float t1 = sacc[1][tsl][r];
        float t2 = sacc[2][tsl][r];
        float t3 = sacc[3][tsl][r];
        float e0 = __builtin_amdgcn_exp2f(t0);
        float e1 = __builtin_amdgcn_exp2f(t1);
        float e2 = __builtin_amdgcn_exp2f(t2);
        float e3 = __builtin_amdgcn_exp2f(t3);
        float sum = (e0 + e1) + (e2 + e3);
        float inv = __builtin_amdgcn_rcpf(sum);
        float l2s = __builtin_amdgcn_logf(sum);
        float w0 = e0 * inv, w1 = e1 * inv, w2 = e2 * inv, w3 = e3 * inv;
        float entv = (w0 * t0 + w1 * t1 + w2 * t2 + w3 * t3 - l2s) * LN2;
        __builtin_nontemporal_store(entv, entp + r * Se + ch * 32 + tsl * 16);
        int pof = (lg * 4 + r) * 36 + tsl * 16 + lr;
        Pw[0 * 576 + pof] = f2b(w0);
        Pw[1 * 576 + pof] = f2b(w1);
        Pw[2 * 576 + pof] = f2b(w2);
        Pw[3 * 576 + pof] = f2b(w3);
      }
    }

#pragma unroll
    for (int c = 0; c < 4; ++c) {
      union { bf16x4 hh[2]; bf16x8 v; } pu;
      pu.hh[0] = *(const bf16x4*)(Pw + c * 576 + lr * 36 + lg * 8);
      pu.hh[1] = *(const bf16x4*)(Pw + c * 576 + lr * 36 + lg * 8 + 4);
      bf16x8 pf = pu.v;
#pragma unroll
      for (int dsu = 0; dsu < 4; ++dsu)
        oacc[c][dsu] = MFMA16(pf, vf[c * 4 + dsu], oacc[c][dsu]);
    }

    if (ch < 7) {
#pragma unroll
      for (int i = 0; i < 16; ++i) kf[i] = kfn[i];
    }
  }

#pragma unroll
  for (int c = 0; c < 4; ++c)
#pragma unroll
    for (int dsu = 0; dsu < 4; ++dsu)
#pragma unroll
      for (int r = 0; r < 4; ++r) {
        int s = s0 + lg * 4 + r;
        attn[((c * B + b) * (long)S + s) * D + h * 64 + dsu * 16 + lr] =
            f2b(oacc[c][dsu][r]);
      }
}

extern "C" void kernel_launch(void* const* d_in, const int* in_sizes, int n_in,
                              void* d_out, int out_size, void* d_ws, size_t ws_size,
                              hipStream_t stream) {
  const float* hs  = (const float*)d_in[0];  // [8,4096,1024]
  const float* ehs = (const float*)d_in[1];  // [8,256,2048]
  const float* Wq  = (const float*)d_in[2];  // [1024,1024]
  const float* Wk  = (const float*)d_in[3];  // [2048,1024]
  const float* Wv  = (const float*)d_in[4];  // [2048,1024]
  const float* Wo  = (const float*)d_in[5];  // [1024,1024]
  const float* bo  = (const float*)d_in[6];  // [1024]
  float* out = (float*)d_out;
  float* ent = out + (size_t)8 * 4096 * 1024;

  char* ws = (char*)d_ws;
  u16* hsb   = (u16*)(ws);              // 67,108,864 B (bf16 hs; reused as attn out)
  u16* ehsb  = (u16*)(ws + 67108864);   //  8,388,608 B (dead after KV GEMM)
  u16* kfrag = (u16*)(ws + 67108864);   //  4,194,304 B (overwrites ehsb after last use)
  u16* vfrag = (u16*)(ws + 71303168);   //  4,194,304 B
  u16* wqT   = (u16*)(ws + 75497472);   //  2,097,152 B
  u16* wkT   = (u16*)(ws + 77594624);   //  4,194,304 B  \ adjacent: acts as single
  u16* wvT   = (u16*)(ws + 81788928);   //  4,194,304 B  / Bt[2048][2048] for KV GEMM
  u16* woT   = (u16*)(ws + 85983232);   //  2,097,152 B
  u16* qb    = (u16*)(ws + 88080384);   // 67,108,864 B
  u16* kvb   = (u16*)(ws + 155189248);  //  8,388,608 B  [2048][2048]: k | v
  u16* vtb   = (u16*)(ws + 163577856);  //  4,194,304 B  (end: 167,772,160)

  const float QSCALE = 0.125f * 1.44269504f;  // attn.scale * log2(e)

  cvt_f32_bf16<<<2048, 256, 0, stream>>>(hs, hsb, (8 * 4096 * 1024) / 4);
  cvt_f32_bf16<<<512, 256, 0, stream>>>(ehs, ehsb, (8 * 256 * 2048) / 4);
  wtrans<<<1024, 256, 0, stream>>>(Wq, wqT, 1024, 1024);
  wtrans<<<2048, 256, 0, stream>>>(Wk, wkT, 2048, 1024);
  wtrans<<<2048, 256, 0, stream>>>(Wv, wvT, 2048, 1024);
  wtrans<<<1024, 256, 0, stream>>>(Wo, woT, 1024, 1024);
  // q = (hs @ Wq) * scale*log2e   -- 256^2 stage-ahead GEMM, 512 blocks
  gemm256<0><<<(32768 / 256) * (1024 / 256), 512, 0, stream>>>(
      hsb, wqT, qb, nullptr, nullptr, nullptr, 32768, 1024, 1024, QSCALE);
  // [k|v] = ehs @ [Wk|Wv]  -- fused, 128^2 GEMM, 256 blocks (full GPU)
  gemm_bt<<<(2048 / 128) * (2048 / 128), 256, 0, stream>>>(
      ehsb, wkT, kvb, 2048, 2048, 2048, 1.0f);
  vtrans<<<2048, 256, 0, stream>>>(kvb, vtb);          // v-half, scaled by C/Se
  kfrag_build<<<1024, 256, 0, stream>>>(kvb, kfrag);   // k-half (ehsb now dead)
  vfrag_build<<<1024, 256, 0, stream>>>(vtb, vfrag);
  // fused component-softmax attention (attn out -> hsb region, entropy -> d_out)
  attn_fused<<<2048, 256, 0, stream>>>(qb, kfrag, vfrag, hsb, ent);
  // out = attn @ Wo + bo + hs   -- 256^2 stage-ahead GEMM
  gemm256<1><<<(32768 / 256) * (1024 / 256), 512, 0, stream>>>(
      hsb, woT, nullptr, out, bo, hs, 32768, 1024, 1024, 1.0f);
}